// Round 2
// 466.338 us; speedup vs baseline: 1.0631x; 1.0631x over previous
//
#include <hip/hip_runtime.h>
#include <hip/hip_bf16.h>

#define N_USERS    50000
#define N_ENTITIES 150000
#define N_NODES_C  200000
#define BATCH_C    4096
#define N_EDGES_C  3200000

// two-stage edge sort params
#define CHUNK   7168            // edges per sort1 block (LDS 57.3 KB buf)
#define SG_SH   9               // supergroup = 512 nodes
#define NSG     391             // ceil(200000/512)
#define MAXCHK  448             // max chunks (3.2M/7168 = 447)
#define S2CAP   12288           // sort2 LDS edge capacity (expected ~8192/sg)

typedef __attribute__((ext_vector_type(8))) short short8;
typedef __attribute__((ext_vector_type(4))) float float4v;

// Workspace (~67 MB; proven safe < 76.8 MB):
//   row_ptr : int [200001+pad]      0.80 MB   (written by sort2, coalesced)
//   cntarr  : int [448*391]         0.70 MB   (chunk-major per-sg counts)
//   offarr  : int [448*391]         0.70 MB
//   sgoff   : int [512]             2 KB      (supergroup global starts)
//   edges   : uint [3.2M]          12.8 MB    (nb<<14 | val_q14, node-sorted CSR)
//   fb16    : ushort[200000*64]    25.6 MB    (bf16 node features)
//   region  : 25.69 MB — tmp (uint2 sorted runs) then h1 (bf16 layer-1 out)

__device__ __forceinline__ unsigned short f32_to_bf16_bits(float x) {
    unsigned u = __float_as_uint(x);
    unsigned r = (u + 0x7fffu + ((u >> 16) & 1u)) >> 16;   // RNE
    return (unsigned short)r;
}

// ---------- bf16 node-feature table ----------
__global__ __launch_bounds__(256) void tobf16_k(const float* __restrict__ uw,
                                                const float* __restrict__ ew,
                                                unsigned short* __restrict__ fb)
{
    int idx = blockIdx.x * 256 + threadIdx.x;
    if (idx >= N_NODES_C * 64) return;
    const int split = N_USERS * 64;
    float x = (idx < split) ? uw[idx] : ew[idx - split];
    fb[idx] = f32_to_bf16_bits(x);
}

// ---------- stage 1: chunk-local counting sort by supergroup ----------
__global__ __launch_bounds__(256) void sort1_k(
    const int* __restrict__ target, const int* __restrict__ neighbor,
    const float* __restrict__ values,
    uint2* __restrict__ tmp, int* __restrict__ cntarr, int* __restrict__ offarr,
    int n_edges)
{
    __shared__ uint2 buf[CHUNK];            // 57.3 KB
    __shared__ int cnt[NSG], off[NSG], pos[NSG];
    int c = blockIdx.x;
    int base = c * CHUNK;
    int ccount = min(CHUNK, n_edges - base);
    for (int i = threadIdx.x; i < NSG; i += 256) { cnt[i] = 0; pos[i] = 0; }
    __syncthreads();
    for (int i = threadIdx.x; i < ccount; i += 256)
        atomicAdd(&cnt[target[base + i] >> SG_SH], 1);
    __syncthreads();
    if (threadIdx.x < 64) {                 // wave-0 exclusive scan of cnt
        int l = threadIdx.x;
        const int PER = (NSG + 63) / 64;    // 7
        int s0 = l * PER, s1 = min(s0 + PER, NSG);
        int sum = 0;
        for (int i = s0; i < s1; i++) sum += cnt[i];
        int run = sum;
        #pragma unroll
        for (int o = 1; o < 64; o <<= 1) { int v = __shfl_up(run, o); if (l >= o) run += v; }
        int excl = run - sum;
        for (int i = s0; i < s1; i++) { off[i] = excl; excl += cnt[i]; }
    }
    __syncthreads();
    for (int i = threadIdx.x; i < ccount; i += 256) {
        int t  = target[base + i];
        int sg = t >> SG_SH;
        unsigned q = (unsigned)fminf(values[base + i] * 16384.f + 0.5f, 16383.f);
        unsigned w = ((unsigned)neighbor[base + i] << 14) | q;
        int p = off[sg] + atomicAdd(&pos[sg], 1);
        buf[p] = make_uint2(w, (unsigned)t);
    }
    __syncthreads();
    for (int i = threadIdx.x; i < ccount; i += 256)
        tmp[(size_t)c * CHUNK + i] = buf[i];
    for (int i = threadIdx.x; i < NSG; i += 256) {
        cntarr[c * NSG + i] = cnt[i];
        offarr[c * NSG + i] = off[i];
    }
}

// ---------- supergroup prefix: sgoff[s] = global CSR start of supergroup s ----------
__global__ __launch_bounds__(512) void sgscan_k(const int* __restrict__ cntarr,
                                                int* __restrict__ sgoff, int nchunks)
{
    __shared__ int part[512];
    int t = threadIdx.x;
    int sum = 0;
    if (t < NSG)
        for (int c = 0; c < nchunks; c++) sum += cntarr[c * NSG + t];
    part[t] = sum;
    __syncthreads();
    for (int off = 1; off < 512; off <<= 1) {
        int w = (t >= off) ? part[t - off] : 0;
        __syncthreads();
        part[t] += w;
        __syncthreads();
    }
    if (t < NSG) sgoff[t] = part[t] - sum;          // exclusive
    if (t == NSG - 1) sgoff[NSG] = part[t];          // total = n_edges
}

// ---------- stage 2: per-supergroup node-exact placement + row_ptr build ----------
__global__ __launch_bounds__(256) void sort2_k(
    const uint2* __restrict__ tmp, const int* __restrict__ cntarr,
    const int* __restrict__ offarr, const int* __restrict__ sgoff,
    int* __restrict__ row_ptr, unsigned* __restrict__ edges, int nchunks)
{
    __shared__ unsigned ebuf[S2CAP];        // 49.2 KB
    __shared__ unsigned short tbuf[S2CAP];  // 24.6 KB
    __shared__ int cnt[512];
    __shared__ int cur[512];
    __shared__ int rp[513];
    __shared__ int pre[MAXCHK + 1];
    __shared__ int soff[MAXCHK];
    int s = blockIdx.x;
    int node0 = s << SG_SH;
    int nn = min(512, N_NODES_C - node0);
    int sgstart = sgoff[s];
    for (int i = threadIdx.x; i < 512; i += 256) { cnt[i] = 0; cur[i] = 0; }
    for (int c = threadIdx.x; c < nchunks; c += 256) {
        pre[c]  = cntarr[c * NSG + s];
        soff[c] = offarr[c * NSG + s];
    }
    __syncthreads();
    if (threadIdx.x < 64) {                 // wave-0 exclusive scan of pre
        int l = threadIdx.x;
        int PER = (nchunks + 63) >> 6;      // 7
        int s0 = l * PER, s1 = min(s0 + PER, nchunks);
        int vals[8];
        int sum = 0;
        for (int i = s0; i < s1; i++) { vals[i - s0] = pre[i]; sum += vals[i - s0]; }
        int run = sum;
        #pragma unroll
        for (int o = 1; o < 64; o <<= 1) { int v = __shfl_up(run, o); if (l >= o) run += v; }
        int excl = run - sum;
        for (int i = s0; i < s1; i++) { int t = vals[i - s0]; pre[i] = excl; excl += t; }
        if (l == 63) pre[nchunks] = excl;
    }
    __syncthreads();
    int sgcnt = pre[nchunks];
    // pass 1: gather edges to LDS + count per node
    for (int e = threadIdx.x; e < sgcnt; e += 256) {
        int lo = 0, hi = nchunks;
        while (hi - lo > 1) {
            int mid = (lo + hi) >> 1;
            if (pre[mid] <= e) lo = mid; else hi = mid;
        }
        uint2 ed = tmp[(size_t)lo * CHUNK + soff[lo] + (e - pre[lo])];
        int tl = (int)ed.y - node0;
        atomicAdd(&cnt[tl], 1);
        if (e < S2CAP) { ebuf[e] = ed.x; tbuf[e] = (unsigned short)tl; }
    }
    __syncthreads();
    if (threadIdx.x < 64) {                 // wave-0 exclusive scan of cnt[512]
        int l = threadIdx.x;
        int s0 = l * 8, s1 = s0 + 8;
        int vals[8];
        int sum = 0;
        for (int i = s0; i < s1; i++) { vals[i - s0] = cnt[i]; sum += vals[i - s0]; }
        int run = sum;
        #pragma unroll
        for (int o = 1; o < 64; o <<= 1) { int v = __shfl_up(run, o); if (l >= o) run += v; }
        int excl = run - sum;
        for (int i = s0; i < s1; i++) { rp[i] = excl; excl += vals[i - s0]; }
        if (l == 63) rp[512] = excl;
    }
    __syncthreads();
    // write row_ptr (coalesced, block-private)
    for (int i = threadIdx.x; i < nn; i += 256) row_ptr[node0 + i] = sgstart + rp[i];
    if (s == NSG - 1 && threadIdx.x == 0) row_ptr[N_NODES_C] = sgstart + sgcnt;
    // pass 2: place edges into block-private global segment
    int lim = min(sgcnt, S2CAP);
    for (int e = threadIdx.x; e < lim; e += 256) {
        int tl  = tbuf[e];
        int old = atomicAdd(&cur[tl], 1);
        edges[sgstart + rp[tl] + old] = ebuf[e];
    }
    // rare overflow path: re-read tmp for e >= S2CAP
    for (int e = S2CAP + threadIdx.x; e < sgcnt; e += 256) {
        int lo = 0, hi = nchunks;
        while (hi - lo > 1) {
            int mid = (lo + hi) >> 1;
            if (pre[mid] <= e) lo = mid; else hi = mid;
        }
        uint2 ed = tmp[(size_t)lo * CHUNK + soff[lo] + (e - pre[lo])];
        int tl  = (int)ed.y - node0;
        int old = atomicAdd(&cur[tl], 1);
        edges[sgstart + rp[tl] + old] = ed.x;
    }
}

// ---------- layer 1: quad-node gather pull + MFMA dense transform ----------
// SPS=136 is REQUIRED: each row holds 128 bf16 k-values (64 sum-path +
// 64 product-path); 136 = 128 + 8 pad, 272 B stride = bank +4/row rotation.
// LDS 52.7 KB -> 3 blocks/CU. Latency hiding comes from ILP instead:
// 4 independent gather streams x unroll-4 = 16 gathers in flight per wave.
#define SPS 136
__global__ __launch_bounds__(512, 6) void layer1_pull_k(
    const unsigned short* __restrict__ fb,
    const int* __restrict__ row_ptr, const unsigned int* __restrict__ edges,
    const float* __restrict__ W1, const float* __restrict__ b1,
    const float* __restrict__ W2, const float* __restrict__ b2,
    __hip_bfloat16* __restrict__ h1out, int n_nodes)
{
    __shared__ __align__(16) short wt[64 * SPS];    // 17.4 KB
    __shared__ __align__(16) short sp[128 * SPS];   // 34.8 KB
    __shared__ float sbias[64];

    for (int idx = threadIdx.x; idx < 64 * 64; idx += 512) {
        int kp = idx >> 6;
        int n  = idx & 63;
        int k0 = kp * 2, k1 = k0 + 1;
        float w0 = (k0 < 64) ? W1[k0 * 64 + n] : W2[(k0 - 64) * 64 + n];
        float w1 = (k1 < 64) ? W1[k1 * 64 + n] : W2[(k1 - 64) * 64 + n];
        *(unsigned*)&wt[n * SPS + k0] =
            ((unsigned)f32_to_bf16_bits(w1) << 16) | f32_to_bf16_bits(w0);
    }
    if (threadIdx.x < 64) sbias[threadIdx.x] = b1[threadIdx.x] + b2[threadIdx.x];
    __syncthreads();

    int wv   = threadIdx.x >> 6;
    int lane = threadIdx.x & 63;
    int g    = lane >> 4;
    int q    = lane & 15;
    const uint2* fb2 = (const uint2*)fb;

    int nb0 = blockIdx.x * 128;
    const float QS = 1.f / 16384.f;

    for (int i = 0; i < 16; i += 4) {
        int mA = wv * 16 + i;
        int nodeBase = nb0 + mA;

        int es0 = 0, ee0 = 0, es1 = 0, ee1 = 0, es2 = 0, ee2 = 0, es3 = 0, ee3 = 0;
        if (nodeBase     < n_nodes) { es0 = row_ptr[nodeBase];     ee0 = row_ptr[nodeBase + 1]; }
        if (nodeBase + 1 < n_nodes) { es1 = row_ptr[nodeBase + 1]; ee1 = row_ptr[nodeBase + 2]; }
        if (nodeBase + 2 < n_nodes) { es2 = row_ptr[nodeBase + 2]; ee2 = row_ptr[nodeBase + 3]; }
        if (nodeBase + 3 < n_nodes) { es3 = row_ptr[nodeBase + 3]; ee3 = row_ptr[nodeBase + 4]; }

        float ac[4][4];
        #pragma unroll
        for (int s = 0; s < 4; s++)
            #pragma unroll
            for (int c = 0; c < 4; c++) ac[s][c] = 0.f;

        int b0 = es0, b1c = es1, b2c = es2, b3c = es3;
        while (b0 < ee0 || b1c < ee1 || b2c < ee2 || b3c < ee3) {
            int c0 = ee0 - b0;  c0 = c0 < 0 ? 0 : (c0 > 64 ? 64 : c0);
            int c1 = ee1 - b1c; c1 = c1 < 0 ? 0 : (c1 > 64 ? 64 : c1);
            int c2 = ee2 - b2c; c2 = c2 < 0 ? 0 : (c2 > 64 ? 64 : c2);
            int c3 = ee3 - b3c; c3 = c3 < 0 ? 0 : (c3 > 64 ? 64 : c3);
            unsigned ev0 = (lane < c0) ? edges[b0 + lane]  : 0u;
            unsigned ev1 = (lane < c1) ? edges[b1c + lane] : 0u;
            unsigned ev2 = (lane < c2) ? edges[b2c + lane] : 0u;
            unsigned ev3 = (lane < c3) ? edges[b3c + lane] : 0u;
            int jm0 = (c0 + 3) >> 2;
            int jm1 = (c1 + 3) >> 2;
            int jm2 = (c2 + 3) >> 2;
            int jm3 = (c3 + 3) >> 2;
            int jm = max(max(jm0, jm1), max(jm2, jm3));
            #pragma unroll 4
            for (int j = 0; j < jm; j++) {
                unsigned w0 = (j < jm0) ? (unsigned)__shfl((int)ev0, j * 4 + g) : 0u;
                unsigned w1 = (j < jm1) ? (unsigned)__shfl((int)ev1, j * 4 + g) : 0u;
                unsigned w2 = (j < jm2) ? (unsigned)__shfl((int)ev2, j * 4 + g) : 0u;
                unsigned w3 = (j < jm3) ? (unsigned)__shfl((int)ev3, j * 4 + g) : 0u;
                uint2 d0 = fb2[(size_t)(w0 >> 14) * 16 + q];   // w=0 -> row0, v=0
                uint2 d1 = fb2[(size_t)(w1 >> 14) * 16 + q];
                uint2 d2 = fb2[(size_t)(w2 >> 14) * 16 + q];
                uint2 d3 = fb2[(size_t)(w3 >> 14) * 16 + q];
                float v0 = (float)(w0 & 16383u) * QS;
                float v1 = (float)(w1 & 16383u) * QS;
                float v2 = (float)(w2 & 16383u) * QS;
                float v3 = (float)(w3 & 16383u) * QS;
                ac[0][0] += v0 * __uint_as_float(d0.x << 16);
                ac[0][1] += v0 * __uint_as_float(d0.x & 0xffff0000u);
                ac[0][2] += v0 * __uint_as_float(d0.y << 16);
                ac[0][3] += v0 * __uint_as_float(d0.y & 0xffff0000u);
                ac[1][0] += v1 * __uint_as_float(d1.x << 16);
                ac[1][1] += v1 * __uint_as_float(d1.x & 0xffff0000u);
                ac[1][2] += v1 * __uint_as_float(d1.y << 16);
                ac[1][3] += v1 * __uint_as_float(d1.y & 0xffff0000u);
                ac[2][0] += v2 * __uint_as_float(d2.x << 16);
                ac[2][1] += v2 * __uint_as_float(d2.x & 0xffff0000u);
                ac[2][2] += v2 * __uint_as_float(d2.y << 16);
                ac[2][3] += v2 * __uint_as_float(d2.y & 0xffff0000u);
                ac[3][0] += v3 * __uint_as_float(d3.x << 16);
                ac[3][1] += v3 * __uint_as_float(d3.x & 0xffff0000u);
                ac[3][2] += v3 * __uint_as_float(d3.y << 16);
                ac[3][3] += v3 * __uint_as_float(d3.y & 0xffff0000u);
            }
            b0 += 64; b1c += 64; b2c += 64; b3c += 64;
        }
        // reduce across the 4 lane-groups (bits 4,5 of lane id)
        #pragma unroll
        for (int s = 0; s < 4; s++)
            #pragma unroll
            for (int c = 0; c < 4; c++) {
                ac[s][c] += __shfl_xor(ac[s][c], 16);
                ac[s][c] += __shfl_xor(ac[s][c], 32);
            }

        // epilogue: g in {0,1} handles rows mA,mA+1; g in {2,3} rows mA+2,mA+3
        // even g = sum path (k<64), odd g = product path (k>=64). All 4 groups busy.
        int half = g >> 1;
        int prod = g & 1;
        int r0 = mA + (half << 1);
        int r1 = r0 + 1;
        int nd0 = nb0 + r0, nd1 = nb0 + r1;
        uint2 d0 = make_uint2(0u, 0u), d1 = make_uint2(0u, 0u);
        if (nd0 < n_nodes) d0 = fb2[(size_t)nd0 * 16 + q];
        if (nd1 < n_nodes) d1 = fb2[(size_t)nd1 * 16 + q];
        // constant-index selects (avoid runtime-indexed register array -> scratch)
        float a00 = half ? ac[2][0] : ac[0][0];
        float a01 = half ? ac[2][1] : ac[0][1];
        float a02 = half ? ac[2][2] : ac[0][2];
        float a03 = half ? ac[2][3] : ac[0][3];
        float a10 = half ? ac[3][0] : ac[1][0];
        float a11 = half ? ac[3][1] : ac[1][1];
        float a12 = half ? ac[3][2] : ac[1][2];
        float a13 = half ? ac[3][3] : ac[1][3];
        float f00 = __uint_as_float(d0.x << 16);
        float f01 = __uint_as_float(d0.x & 0xffff0000u);
        float f02 = __uint_as_float(d0.y << 16);
        float f03 = __uint_as_float(d0.y & 0xffff0000u);
        float f10 = __uint_as_float(d1.x << 16);
        float f11 = __uint_as_float(d1.x & 0xffff0000u);
        float f12 = __uint_as_float(d1.y << 16);
        float f13 = __uint_as_float(d1.y & 0xffff0000u);
        float x00 = prod ? f00 * a00 : f00 + a00;
        float x01 = prod ? f01 * a01 : f01 + a01;
        float x02 = prod ? f02 * a02 : f02 + a02;
        float x03 = prod ? f03 * a03 : f03 + a03;
        float x10 = prod ? f10 * a10 : f10 + a10;
        float x11 = prod ? f11 * a11 : f11 + a11;
        float x12 = prod ? f12 * a12 : f12 + a12;
        float x13 = prod ? f13 * a13 : f13 + a13;
        uint2 pk;
        pk.x = ((unsigned)f32_to_bf16_bits(x01) << 16) | f32_to_bf16_bits(x00);
        pk.y = ((unsigned)f32_to_bf16_bits(x03) << 16) | f32_to_bf16_bits(x02);
        *(uint2*)&sp[r0 * SPS + prod * 64 + q * 4] = pk;
        pk.x = ((unsigned)f32_to_bf16_bits(x11) << 16) | f32_to_bf16_bits(x10);
        pk.y = ((unsigned)f32_to_bf16_bits(x13) << 16) | f32_to_bf16_bits(x12);
        *(uint2*)&sp[r1 * SPS + prod * 64 + q * 4] = pk;
    }

    // sp rows are wave-private (wave wv writes and reads rows wv*16..wv*16+15),
    // so a full __syncthreads is not needed — just drain this wave's LDS writes.
    // Fast waves proceed to MFMA without waiting for the block's slowest wave.
    __builtin_amdgcn_wave_barrier();
    asm volatile("s_waitcnt lgkmcnt(0)" ::: "memory");
    __builtin_amdgcn_wave_barrier();

    float4v c0, c1, c2, c3;
    {
        float bv0 = sbias[q];
        float bv1 = sbias[16 + q];
        float bv2 = sbias[32 + q];
        float bv3 = sbias[48 + q];
        c0 = (float4v){bv0, bv0, bv0, bv0};
        c1 = (float4v){bv1, bv1, bv1, bv1};
        c2 = (float4v){bv2, bv2, bv2, bv2};
        c3 = (float4v){bv3, bv3, bv3, bv3};
    }
    #pragma unroll
    for (int kk = 0; kk < 4; kk++) {
        int ko = kk * 32 + g * 8;
        short8 a = *(const short8*)&sp[(wv * 16 + q) * SPS + ko];
        short8 bb0 = *(const short8*)&wt[(q)      * SPS + ko];
        short8 bb1 = *(const short8*)&wt[(16 + q) * SPS + ko];
        short8 bb2 = *(const short8*)&wt[(32 + q) * SPS + ko];
        short8 bb3 = *(const short8*)&wt[(48 + q) * SPS + ko];
        c0 = __builtin_amdgcn_mfma_f32_16x16x32_bf16(a, bb0, c0, 0, 0, 0);
        c1 = __builtin_amdgcn_mfma_f32_16x16x32_bf16(a, bb1, c1, 0, 0, 0);
        c2 = __builtin_amdgcn_mfma_f32_16x16x32_bf16(a, bb2, c2, 0, 0, 0);
        c3 = __builtin_amdgcn_mfma_f32_16x16x32_bf16(a, bb3, c3, 0, 0, 0);
    }

    float ss[4];
    #pragma unroll
    for (int r = 0; r < 4; r++) {
        c0[r] = (c0[r] > 0.f) ? c0[r] : 0.01f * c0[r];
        c1[r] = (c1[r] > 0.f) ? c1[r] : 0.01f * c1[r];
        c2[r] = (c2[r] > 0.f) ? c2[r] : 0.01f * c2[r];
        c3[r] = (c3[r] > 0.f) ? c3[r] : 0.01f * c3[r];
        ss[r] = c0[r]*c0[r] + c1[r]*c1[r] + c2[r]*c2[r] + c3[r]*c3[r];
        #pragma unroll
        for (int mm = 1; mm < 16; mm <<= 1) ss[r] += __shfl_xor(ss[r], mm);
        ss[r] = 1.f / fmaxf(sqrtf(ss[r]), 1e-12f);
    }
    #pragma unroll
    for (int r = 0; r < 4; r++) {
        int node_r = nb0 + wv * 16 + g * 4 + r;
        if (node_r >= n_nodes) continue;
        size_t row = (size_t)node_r * 64;
        h1out[row +      q] = __float2bfloat16(c0[r] * ss[r]);
        h1out[row + 16 + q] = __float2bfloat16(c1[r] * ss[r]);
        h1out[row + 32 + q] = __float2bfloat16(c2[r] * ss[r]);
        h1out[row + 48 + q] = __float2bfloat16(c3[r] * ss[r]);
    }
}

// ---------- inline layer2 (64->32) for one node, aggregation pulled on the fly ----------
__device__ __forceinline__ float layer2_row(
    const __hip_bfloat16* __restrict__ h1,
    const int* __restrict__ row_ptr, const unsigned int* __restrict__ edges,
    const float* sW1, const float* sW2, const float* sb,
    int node, int lane)
{
    int es = row_ptr[node];
    int ee = row_ptr[node + 1];
    const float QS = 1.f / 16384.f;
    float g = 0.f;
    for (int base = es; base < ee; base += 64) {
        int cnt = min(64, ee - base);
        unsigned ev = (lane < cnt) ? edges[base + lane] : 0u;
        int j = 0;
        for (; j + 4 <= cnt; j += 4) {
            unsigned e0 = (unsigned)__shfl((int)ev, j);
            unsigned e1 = (unsigned)__shfl((int)ev, j + 1);
            unsigned e2 = (unsigned)__shfl((int)ev, j + 2);
            unsigned e3 = (unsigned)__shfl((int)ev, j + 3);
            float f0 = __bfloat162float(h1[(size_t)(e0 >> 14) * 64 + lane]);
            float f1 = __bfloat162float(h1[(size_t)(e1 >> 14) * 64 + lane]);
            float f2 = __bfloat162float(h1[(size_t)(e2 >> 14) * 64 + lane]);
            float f3 = __bfloat162float(h1[(size_t)(e3 >> 14) * 64 + lane]);
            g += (float)(e0 & 16383u) * QS * f0 + (float)(e1 & 16383u) * QS * f1
               + (float)(e2 & 16383u) * QS * f2 + (float)(e3 & 16383u) * QS * f3;
        }
        for (; j < cnt; j++) {
            unsigned e0 = (unsigned)__shfl((int)ev, j);
            float f0 = __bfloat162float(h1[(size_t)(e0 >> 14) * 64 + lane]);
            g += (float)(e0 & 16383u) * QS * f0;
        }
    }
    float f = __bfloat162float(h1[(size_t)node * 64 + lane]);
    float s = f + g;
    float p = f * g;
    int j = lane & 31;
    float acc = sb[j];
    #pragma unroll
    for (int k = 0; k < 64; k++) {
        float sk = __shfl(s, k);
        float pk = __shfl(p, k);
        acc += sk * sW1[k * 32 + j] + pk * sW2[k * 32 + j];
    }
    acc = (acc > 0.f) ? acc : 0.01f * acc;
    float sq = acc * acc;
    #pragma unroll
    for (int m = 1; m < 32; m <<= 1) sq += __shfl_xor(sq, m);
    return acc / fmaxf(sqrtf(sq), 1e-12f);
}

__global__ __launch_bounds__(256) void score_k(
    const float* __restrict__ uw, const float* __restrict__ ew,
    const __hip_bfloat16* __restrict__ h1,
    const int* __restrict__ row_ptr, const unsigned int* __restrict__ edges,
    const float* __restrict__ W1b, const float* __restrict__ b1b,
    const float* __restrict__ W2b, const float* __restrict__ b2b,
    const int* __restrict__ uid, const int* __restrict__ pid,
    const int* __restrict__ nid, float* __restrict__ out)
{
    __shared__ float sW1[64 * 32];
    __shared__ float sW2[64 * 32];
    __shared__ float sb[32];
    for (int i = threadIdx.x; i < 64 * 32; i += 256) { sW1[i] = W1b[i]; sW2[i] = W2b[i]; }
    if (threadIdx.x < 32) sb[threadIdx.x] = b1b[threadIdx.x] + b2b[threadIdx.x];
    __syncthreads();

    int wave = threadIdx.x >> 6;
    int lane = threadIdx.x & 63;
    int i = blockIdx.x * 4 + wave;
    if (i >= BATCH_C) return;

    int un = uid[i];
    int pe = pid[i];
    int ne = nid[i];
    int pn = N_USERS + pe;
    int nn = N_USERS + ne;

    float acc01p, acc01n;
    {
        float u  = uw[(size_t)un * 64 + lane];
        float pv = ew[(size_t)pe * 64 + lane];
        float nv = ew[(size_t)ne * 64 + lane];
        acc01p = u * pv;
        acc01n = u * nv;
        float u1 = __bfloat162float(h1[(size_t)un * 64 + lane]);
        acc01p += u1 * __bfloat162float(h1[(size_t)pn * 64 + lane]);
        acc01n += u1 * __bfloat162float(h1[(size_t)nn * 64 + lane]);
    }

    float h2u = layer2_row(h1, row_ptr, edges, sW1, sW2, sb, un, lane);
    float h2p = layer2_row(h1, row_ptr, edges, sW1, sW2, sb, pn, lane);
    float h2n = layer2_row(h1, row_ptr, edges, sW1, sW2, sb, nn, lane);
    float p2 = h2u * h2p;
    float n2 = h2u * h2n;
    #pragma unroll
    for (int m = 1; m < 32; m <<= 1) { p2 += __shfl_xor(p2, m); n2 += __shfl_xor(n2, m); }

    #pragma unroll
    for (int m = 1; m < 64; m <<= 1) { acc01p += __shfl_xor(acc01p, m); acc01n += __shfl_xor(acc01n, m); }

    if (lane == 0) {
        out[i]           = acc01p + p2;
        out[BATCH_C + i] = acc01n + n2;
    }
}

extern "C" void kernel_launch(void* const* d_in, const int* in_sizes, int n_in,
                              void* d_out, int out_size, void* d_ws, size_t ws_size,
                              hipStream_t stream) {
    const float* uw   = (const float*)d_in[0];
    const float* ew   = (const float*)d_in[1];
    const float* W1a  = (const float*)d_in[2];
    const float* b1a  = (const float*)d_in[3];
    const float* W2a  = (const float*)d_in[4];
    const float* b2a  = (const float*)d_in[5];
    const float* W1b  = (const float*)d_in[6];
    const float* b1b  = (const float*)d_in[7];
    const float* W2b  = (const float*)d_in[8];
    const float* b2b  = (const float*)d_in[9];
    const float* values   = (const float*)d_in[10];
    const int*   target   = (const int*)d_in[11];
    const int*   neighbor = (const int*)d_in[12];
    const int*   uid  = (const int*)d_in[13];
    const int*   pid  = (const int*)d_in[14];
    const int*   nid  = (const int*)d_in[15];

    const int n_edges = in_sizes[10];

    char* ws = (char*)d_ws;
    int*  row_ptr    = (int*)ws;   ws += 801792;
    int*  cntarr     = (int*)ws;   ws += 704512;          // 448*391*4 = 700672
    int*  offarr     = (int*)ws;   ws += 704512;
    int*  sgoff      = (int*)ws;   ws += 4096;
    unsigned int*   edges = (unsigned int*)ws;   ws += (size_t)N_EDGES_C * 4;      // 12.8 MB
    unsigned short* fb    = (unsigned short*)ws; ws += (size_t)N_NODES_C * 64 * 2; // 25.6 MB
    uint2*          tmp   = (uint2*)ws;                   // aliased with h1
    __hip_bfloat16* h1    = (__hip_bfloat16*)ws;          // region 25.69 MB

    const int layer_blocks = (N_NODES_C + 127) / 128;     // 1563
    const int conv_blocks  = (N_NODES_C * 64 + 255) / 256;
    const int nchunks      = (n_edges + CHUNK - 1) / CHUNK;   // 447

    // ----- bf16 feature table -----
    tobf16_k<<<conv_blocks, 256, 0, stream>>>(uw, ew, fb);

    // ----- edge sort + CSR build (no global histogram at all) -----
    sort1_k<<<nchunks, 256, 0, stream>>>(target, neighbor, values, tmp, cntarr, offarr, n_edges);
    sgscan_k<<<1, 512, 0, stream>>>(cntarr, sgoff, nchunks);
    sort2_k<<<NSG, 256, 0, stream>>>(tmp, cntarr, offarr, sgoff, row_ptr, edges, nchunks);

    // ----- layer 1 (quad-node pull + MFMA transform) -----
    layer1_pull_k<<<layer_blocks, 512, 0, stream>>>(fb, row_ptr, edges,
                                                    W1a, b1a, W2a, b2a, h1, N_NODES_C);

    // ----- scoring (layer-2 aggregation + transform inline, ~12K nodes) -----
    score_k<<<BATCH_C / 4, 256, 0, stream>>>(uw, ew, h1, row_ptr, edges,
                                             W1b, b1b, W2b, b2b,
                                             uid, pid, nid, (float*)d_out);
}

// Round 4
// 456.670 us; speedup vs baseline: 1.0856x; 1.0212x over previous
//
#include <hip/hip_runtime.h>

#define N_USERS    50000
#define N_ENTITIES 150000
#define N_NODES_C  200000
#define BATCH_C    4096
#define N_EDGES_C  3200000

// edge sort params
#define CHUNK   7168            // edges per scatter block (LDS 57.3 KB buf)
#define SG_SH   9               // supergroup = 512 nodes
#define NSG     391             // ceil(200000/512)
#define MAXCHK  448             // max chunks (3.2M/7168 = 447)

typedef __attribute__((ext_vector_type(2))) _Float16 h2;
typedef __attribute__((ext_vector_type(8))) _Float16 half8;
typedef __attribute__((ext_vector_type(2))) __fp16 fp16x2_s;   // builtin return type
typedef __attribute__((ext_vector_type(4))) float float4v;

// Workspace (~67 MB; proven safe < 76.8 MB):
//   row_ptr : int [200001+pad]      0.80 MB
//   cntarr  : int [448*391]         0.70 MB   (chunk-major per-sg counts)
//   choff   : int [448*391]         0.70 MB   (per-chunk per-sg global dest base)
//   sgoff   : int [512]             2 KB      (supergroup global starts)
//   edges   : uint [3.2M]          12.8 MB    (nb<<14 | val_q14, node-sorted CSR)
//   fb16    : ushort[200000*64]    25.6 MB    (f16 node features)
//   region  : 25.69 MB — tmp2 (uint2 sg-sorted edges) then h1 (f16 layer-1 out)
// Sort flow (NO binary search anywhere):
//   count_k: per-chunk per-sg histogram -> cntarr
//   sgscan_k: sg totals -> sgoff; transposed running prefix -> choff
//   scatter_k: LDS sg-sort chunk, write runs DIRECTLY to sg-contiguous tmp2
//   sort2_k: coalesced read of own sg segment, node-level count/scan/place

__device__ __forceinline__ h2 u2h(unsigned u) {
    union { unsigned u; h2 h; } x; x.u = u; return x.h;
}
__device__ __forceinline__ unsigned pk2h(float a, float b) {
    union { fp16x2_s h; unsigned u; } x;
    x.h = __builtin_amdgcn_cvt_pkrtz(a, b);
    return x.u;
}

// ---------- f16 node-feature table ----------
__global__ __launch_bounds__(256) void tof16_k(const float* __restrict__ uw,
                                               const float* __restrict__ ew,
                                               unsigned short* __restrict__ fb)
{
    int idx = blockIdx.x * 256 + threadIdx.x;
    if (idx >= N_NODES_C * 64) return;
    const int split = N_USERS * 64;
    float x = (idx < split) ? uw[idx] : ew[idx - split];
    _Float16 hx = (_Float16)x;
    fb[idx] = *(unsigned short*)&hx;
}

// ---------- pass A: per-chunk per-supergroup histogram ----------
__global__ __launch_bounds__(256) void count_k(const int* __restrict__ target,
                                               int* __restrict__ cntarr, int n_edges)
{
    __shared__ int cnt[NSG];
    int c = blockIdx.x;
    int base = c * CHUNK;
    int ccount = min(CHUNK, n_edges - base);
    for (int i = threadIdx.x; i < NSG; i += 256) cnt[i] = 0;
    __syncthreads();
    for (int i = threadIdx.x; i < ccount; i += 256)
        atomicAdd(&cnt[target[base + i] >> SG_SH], 1);
    __syncthreads();
    for (int i = threadIdx.x; i < NSG; i += 256)
        cntarr[c * NSG + i] = cnt[i];
}

// ---------- supergroup prefix + per-chunk destination bases ----------
__global__ __launch_bounds__(512) void sgscan_k(const int* __restrict__ cntarr,
                                                int* __restrict__ choff,
                                                int* __restrict__ sgoff, int nchunks)
{
    __shared__ int part[512];
    int t = threadIdx.x;
    int sum = 0;
    if (t < NSG)
        for (int c = 0; c < nchunks; c++) sum += cntarr[c * NSG + t];
    part[t] = sum;
    __syncthreads();
    for (int off = 1; off < 512; off <<= 1) {
        int w = (t >= off) ? part[t - off] : 0;
        __syncthreads();
        part[t] += w;
        __syncthreads();
    }
    int base = part[t] - sum;                        // exclusive
    if (t < NSG) sgoff[t] = base;
    if (t == NSG - 1) sgoff[NSG] = part[t];          // total = n_edges
    if (t < NSG) {
        int run = base;
        for (int c = 0; c < nchunks; c++) {          // coalesced across threads
            choff[c * NSG + t] = run;
            run += cntarr[c * NSG + t];
        }
    }
}

// ---------- pass B: LDS sg-sort + direct scatter to sg-contiguous tmp2 ----------
__global__ __launch_bounds__(256) void scatter_k(
    const int* __restrict__ target, const int* __restrict__ neighbor,
    const float* __restrict__ values, const int* __restrict__ choff_g,
    uint2* __restrict__ tmp2, int n_edges)
{
    __shared__ uint2 buf[CHUNK];            // 57.3 KB
    __shared__ int cnt[NSG], off[NSG], pos[NSG], choff[NSG];
    int c = blockIdx.x;
    int base = c * CHUNK;
    int ccount = min(CHUNK, n_edges - base);
    for (int i = threadIdx.x; i < NSG; i += 256) { cnt[i] = 0; pos[i] = 0; }
    __syncthreads();
    for (int i = threadIdx.x; i < ccount; i += 256)
        atomicAdd(&cnt[target[base + i] >> SG_SH], 1);
    for (int i = threadIdx.x; i < NSG; i += 256)
        choff[i] = choff_g[c * NSG + i];
    __syncthreads();
    if (threadIdx.x < 64) {                 // wave-0 exclusive scan of cnt
        int l = threadIdx.x;
        const int PER = (NSG + 63) / 64;    // 7
        int s0 = l * PER, s1 = min(s0 + PER, NSG);
        int sum = 0;
        for (int i = s0; i < s1; i++) sum += cnt[i];
        int run = sum;
        #pragma unroll
        for (int o = 1; o < 64; o <<= 1) { int v = __shfl_up(run, o); if (l >= o) run += v; }
        int excl = run - sum;
        for (int i = s0; i < s1; i++) { off[i] = excl; excl += cnt[i]; }
    }
    __syncthreads();
    for (int i = threadIdx.x; i < ccount; i += 256) {
        int t  = target[base + i];
        int sg = t >> SG_SH;
        unsigned q = (unsigned)fminf(values[base + i] * 16384.f + 0.5f, 16383.f);
        unsigned w = ((unsigned)neighbor[base + i] << 14) | q;
        int p = off[sg] + atomicAdd(&pos[sg], 1);
        buf[p] = make_uint2(w, (unsigned)t);
    }
    __syncthreads();
    // buf is sg-sorted: run for sg occupies [off[sg], off[sg]+cnt[sg]).
    // Write each run to its final sg-contiguous global slot (coalesced within run).
    for (int i = threadIdx.x; i < ccount; i += 256) {
        uint2 ed = buf[i];
        int sg = (int)(ed.y >> SG_SH);
        tmp2[(size_t)(choff[sg] + (i - off[sg]))] = ed;
    }
}

// ---------- stage 2: per-supergroup node-level CSR build (coalesced reads) ----------
__global__ __launch_bounds__(512) void sort2_k(
    const uint2* __restrict__ tmp2, const int* __restrict__ sgoff,
    int* __restrict__ row_ptr, unsigned* __restrict__ edges)
{
    __shared__ int cnt[512];
    __shared__ int cur[512];
    __shared__ int rp[513];
    int s = blockIdx.x;
    int node0 = s << SG_SH;
    int nn = min(512, N_NODES_C - node0);
    int sgstart = sgoff[s];
    int sgcnt = sgoff[s + 1] - sgstart;
    cnt[threadIdx.x] = 0;
    cur[threadIdx.x] = 0;
    __syncthreads();
    // pass 1: count per node (coalesced segment read)
    for (int e = threadIdx.x; e < sgcnt; e += 512)
        atomicAdd(&cnt[tmp2[(size_t)sgstart + e].y & 511u], 1);
    __syncthreads();
    if (threadIdx.x < 64) {                 // wave-0 exclusive scan of cnt[512]
        int l = threadIdx.x;
        int s0 = l * 8;
        int vals[8];
        int sum = 0;
        for (int i = 0; i < 8; i++) { vals[i] = cnt[s0 + i]; sum += vals[i]; }
        int run = sum;
        #pragma unroll
        for (int o = 1; o < 64; o <<= 1) { int v = __shfl_up(run, o); if (l >= o) run += v; }
        int excl = run - sum;
        for (int i = 0; i < 8; i++) { rp[s0 + i] = excl; excl += vals[i]; }
        if (l == 63) rp[512] = excl;
    }
    __syncthreads();
    for (int i = threadIdx.x; i < nn; i += 512) row_ptr[node0 + i] = sgstart + rp[i];
    if (s == NSG - 1 && threadIdx.x == 0) row_ptr[N_NODES_C] = sgstart + sgcnt;
    // pass 2: place (re-read is L2-hot)
    for (int e = threadIdx.x; e < sgcnt; e += 512) {
        uint2 ed = tmp2[(size_t)sgstart + e];
        int tl = (int)(ed.y & 511u);
        int old = atomicAdd(&cur[tl], 1);
        edges[sgstart + rp[tl] + old] = ed.x;
    }
}

// ---------- layer 1: quad-node gather pull (f16 pk_fma) + MFMA f16 transform ----------
// SPS=136 REQUIRED: each row holds 128 f16 k-values (64 sum + 64 product path).
#define SPS 136
__global__ __launch_bounds__(512, 6) void layer1_pull_k(
    const unsigned short* __restrict__ fb,
    const int* __restrict__ row_ptr, const unsigned int* __restrict__ edges,
    const float* __restrict__ W1, const float* __restrict__ b1,
    const float* __restrict__ W2, const float* __restrict__ b2,
    _Float16* __restrict__ h1out, int n_nodes)
{
    __shared__ __align__(16) short wt[64 * SPS];    // 17.4 KB
    __shared__ __align__(16) short sp[128 * SPS];   // 34.8 KB
    __shared__ float sbias[64];

    for (int idx = threadIdx.x; idx < 64 * 64; idx += 512) {
        int kp = idx >> 6;
        int n  = idx & 63;
        int k0 = kp * 2, k1 = k0 + 1;
        float w0 = (k0 < 64) ? W1[k0 * 64 + n] : W2[(k0 - 64) * 64 + n];
        float w1 = (k1 < 64) ? W1[k1 * 64 + n] : W2[(k1 - 64) * 64 + n];
        *(unsigned*)&wt[n * SPS + k0] = pk2h(w0, w1);
    }
    if (threadIdx.x < 64) sbias[threadIdx.x] = b1[threadIdx.x] + b2[threadIdx.x];
    __syncthreads();

    int wv   = threadIdx.x >> 6;
    int lane = threadIdx.x & 63;
    int g    = lane >> 4;
    int q    = lane & 15;
    const uint2* fb2 = (const uint2*)fb;

    int nb0 = blockIdx.x * 128;
    const float QS = 1.f / 16384.f;

    for (int i = 0; i < 16; i += 4) {
        int mA = wv * 16 + i;
        int nodeBase = nb0 + mA;

        int es0 = 0, ee0 = 0, es1 = 0, ee1 = 0, es2 = 0, ee2 = 0, es3 = 0, ee3 = 0;
        if (nodeBase     < n_nodes) { es0 = row_ptr[nodeBase];     ee0 = row_ptr[nodeBase + 1]; }
        if (nodeBase + 1 < n_nodes) { es1 = row_ptr[nodeBase + 1]; ee1 = row_ptr[nodeBase + 2]; }
        if (nodeBase + 2 < n_nodes) { es2 = row_ptr[nodeBase + 2]; ee2 = row_ptr[nodeBase + 3]; }
        if (nodeBase + 3 < n_nodes) { es3 = row_ptr[nodeBase + 3]; ee3 = row_ptr[nodeBase + 4]; }

        h2 aLo0 = (h2){0, 0}, aHi0 = (h2){0, 0};
        h2 aLo1 = (h2){0, 0}, aHi1 = (h2){0, 0};
        h2 aLo2 = (h2){0, 0}, aHi2 = (h2){0, 0};
        h2 aLo3 = (h2){0, 0}, aHi3 = (h2){0, 0};

        int b0 = es0, b1c = es1, b2c = es2, b3c = es3;
        while (b0 < ee0 || b1c < ee1 || b2c < ee2 || b3c < ee3) {
            int c0 = ee0 - b0;  c0 = c0 < 0 ? 0 : (c0 > 64 ? 64 : c0);
            int c1 = ee1 - b1c; c1 = c1 < 0 ? 0 : (c1 > 64 ? 64 : c1);
            int c2 = ee2 - b2c; c2 = c2 < 0 ? 0 : (c2 > 64 ? 64 : c2);
            int c3 = ee3 - b3c; c3 = c3 < 0 ? 0 : (c3 > 64 ? 64 : c3);
            unsigned ev0 = (lane < c0) ? edges[b0 + lane]  : 0u;
            unsigned ev1 = (lane < c1) ? edges[b1c + lane] : 0u;
            unsigned ev2 = (lane < c2) ? edges[b2c + lane] : 0u;
            unsigned ev3 = (lane < c3) ? edges[b3c + lane] : 0u;
            int jm0 = (c0 + 3) >> 2;
            int jm1 = (c1 + 3) >> 2;
            int jm2 = (c2 + 3) >> 2;
            int jm3 = (c3 + 3) >> 2;
            int jm = max(max(jm0, jm1), max(jm2, jm3));
            #pragma unroll 4
            for (int j = 0; j < jm; j++) {
                // lanes beyond a stream's count loaded 0 -> shfl yields w=0 -> v=0
                unsigned w0 = (unsigned)__shfl((int)ev0, j * 4 + g);
                unsigned w1 = (unsigned)__shfl((int)ev1, j * 4 + g);
                unsigned w2 = (unsigned)__shfl((int)ev2, j * 4 + g);
                unsigned w3 = (unsigned)__shfl((int)ev3, j * 4 + g);
                uint2 d0 = fb2[(size_t)(w0 >> 14) * 16 + q];
                uint2 d1 = fb2[(size_t)(w1 >> 14) * 16 + q];
                uint2 d2 = fb2[(size_t)(w2 >> 14) * 16 + q];
                uint2 d3 = fb2[(size_t)(w3 >> 14) * 16 + q];
                _Float16 v0 = (_Float16)((float)(w0 & 16383u) * QS);
                _Float16 v1 = (_Float16)((float)(w1 & 16383u) * QS);
                _Float16 v2 = (_Float16)((float)(w2 & 16383u) * QS);
                _Float16 v3 = (_Float16)((float)(w3 & 16383u) * QS);
                h2 vv0 = (h2){v0, v0};
                h2 vv1 = (h2){v1, v1};
                h2 vv2 = (h2){v2, v2};
                h2 vv3 = (h2){v3, v3};
                aLo0 += u2h(d0.x) * vv0;  aHi0 += u2h(d0.y) * vv0;
                aLo1 += u2h(d1.x) * vv1;  aHi1 += u2h(d1.y) * vv1;
                aLo2 += u2h(d2.x) * vv2;  aHi2 += u2h(d2.y) * vv2;
                aLo3 += u2h(d3.x) * vv3;  aHi3 += u2h(d3.y) * vv3;
            }
            b0 += 64; b1c += 64; b2c += 64; b3c += 64;
        }

        float ac[4][4];
        ac[0][0] = (float)aLo0.x; ac[0][1] = (float)aLo0.y; ac[0][2] = (float)aHi0.x; ac[0][3] = (float)aHi0.y;
        ac[1][0] = (float)aLo1.x; ac[1][1] = (float)aLo1.y; ac[1][2] = (float)aHi1.x; ac[1][3] = (float)aHi1.y;
        ac[2][0] = (float)aLo2.x; ac[2][1] = (float)aLo2.y; ac[2][2] = (float)aHi2.x; ac[2][3] = (float)aHi2.y;
        ac[3][0] = (float)aLo3.x; ac[3][1] = (float)aLo3.y; ac[3][2] = (float)aHi3.x; ac[3][3] = (float)aHi3.y;
        // reduce across the 4 lane-groups (bits 4,5 of lane id) in f32
        #pragma unroll
        for (int s = 0; s < 4; s++)
            #pragma unroll
            for (int c = 0; c < 4; c++) {
                ac[s][c] += __shfl_xor(ac[s][c], 16);
                ac[s][c] += __shfl_xor(ac[s][c], 32);
            }

        // epilogue: g pairs -> (row-pair, sum/product path); all 4 groups busy
        int hseg = g >> 1;
        int prod = g & 1;
        int r0 = mA + (hseg << 1);
        int r1 = r0 + 1;
        int nd0 = nb0 + r0, nd1 = nb0 + r1;
        uint2 d0 = make_uint2(0u, 0u), d1 = make_uint2(0u, 0u);
        if (nd0 < n_nodes) d0 = fb2[(size_t)nd0 * 16 + q];
        if (nd1 < n_nodes) d1 = fb2[(size_t)nd1 * 16 + q];
        float a00 = hseg ? ac[2][0] : ac[0][0];
        float a01 = hseg ? ac[2][1] : ac[0][1];
        float a02 = hseg ? ac[2][2] : ac[0][2];
        float a03 = hseg ? ac[2][3] : ac[0][3];
        float a10 = hseg ? ac[3][0] : ac[1][0];
        float a11 = hseg ? ac[3][1] : ac[1][1];
        float a12 = hseg ? ac[3][2] : ac[1][2];
        float a13 = hseg ? ac[3][3] : ac[1][3];
        h2 s0l = u2h(d0.x), s0h = u2h(d0.y);
        h2 s1l = u2h(d1.x), s1h = u2h(d1.y);
        float f00 = (float)s0l.x, f01 = (float)s0l.y, f02 = (float)s0h.x, f03 = (float)s0h.y;
        float f10 = (float)s1l.x, f11 = (float)s1l.y, f12 = (float)s1h.x, f13 = (float)s1h.y;
        float x00 = prod ? f00 * a00 : f00 + a00;
        float x01 = prod ? f01 * a01 : f01 + a01;
        float x02 = prod ? f02 * a02 : f02 + a02;
        float x03 = prod ? f03 * a03 : f03 + a03;
        float x10 = prod ? f10 * a10 : f10 + a10;
        float x11 = prod ? f11 * a11 : f11 + a11;
        float x12 = prod ? f12 * a12 : f12 + a12;
        float x13 = prod ? f13 * a13 : f13 + a13;
        uint2 pk;
        pk.x = pk2h(x00, x01);
        pk.y = pk2h(x02, x03);
        *(uint2*)&sp[r0 * SPS + prod * 64 + q * 4] = pk;
        pk.x = pk2h(x10, x11);
        pk.y = pk2h(x12, x13);
        *(uint2*)&sp[r1 * SPS + prod * 64 + q * 4] = pk;
    }

    // sp rows are wave-private: drain this wave's LDS writes only (no block barrier)
    __builtin_amdgcn_wave_barrier();
    asm volatile("s_waitcnt lgkmcnt(0)" ::: "memory");
    __builtin_amdgcn_wave_barrier();

    float4v c0, c1, c2, c3;
    {
        float bv0 = sbias[q];
        float bv1 = sbias[16 + q];
        float bv2 = sbias[32 + q];
        float bv3 = sbias[48 + q];
        c0 = (float4v){bv0, bv0, bv0, bv0};
        c1 = (float4v){bv1, bv1, bv1, bv1};
        c2 = (float4v){bv2, bv2, bv2, bv2};
        c3 = (float4v){bv3, bv3, bv3, bv3};
    }
    #pragma unroll
    for (int kk = 0; kk < 4; kk++) {
        int ko = kk * 32 + g * 8;
        half8 a   = *(const half8*)&sp[(wv * 16 + q) * SPS + ko];
        half8 bb0 = *(const half8*)&wt[(q)      * SPS + ko];
        half8 bb1 = *(const half8*)&wt[(16 + q) * SPS + ko];
        half8 bb2 = *(const half8*)&wt[(32 + q) * SPS + ko];
        half8 bb3 = *(const half8*)&wt[(48 + q) * SPS + ko];
        c0 = __builtin_amdgcn_mfma_f32_16x16x32_f16(a, bb0, c0, 0, 0, 0);
        c1 = __builtin_amdgcn_mfma_f32_16x16x32_f16(a, bb1, c1, 0, 0, 0);
        c2 = __builtin_amdgcn_mfma_f32_16x16x32_f16(a, bb2, c2, 0, 0, 0);
        c3 = __builtin_amdgcn_mfma_f32_16x16x32_f16(a, bb3, c3, 0, 0, 0);
    }

    float ss[4];
    #pragma unroll
    for (int r = 0; r < 4; r++) {
        c0[r] = (c0[r] > 0.f) ? c0[r] : 0.01f * c0[r];
        c1[r] = (c1[r] > 0.f) ? c1[r] : 0.01f * c1[r];
        c2[r] = (c2[r] > 0.f) ? c2[r] : 0.01f * c2[r];
        c3[r] = (c3[r] > 0.f) ? c3[r] : 0.01f * c3[r];
        ss[r] = c0[r]*c0[r] + c1[r]*c1[r] + c2[r]*c2[r] + c3[r]*c3[r];
        #pragma unroll
        for (int mm = 1; mm < 16; mm <<= 1) ss[r] += __shfl_xor(ss[r], mm);
        ss[r] = 1.f / fmaxf(sqrtf(ss[r]), 1e-12f);
    }
    #pragma unroll
    for (int r = 0; r < 4; r++) {
        int node_r = nb0 + wv * 16 + g * 4 + r;
        if (node_r >= n_nodes) continue;
        size_t row = (size_t)node_r * 64;
        h1out[row +      q] = (_Float16)(c0[r] * ss[r]);
        h1out[row + 16 + q] = (_Float16)(c1[r] * ss[r]);
        h1out[row + 32 + q] = (_Float16)(c2[r] * ss[r]);
        h1out[row + 48 + q] = (_Float16)(c3[r] * ss[r]);
    }
}

// ---------- inline layer2 (64->32) for one node ----------
__device__ __forceinline__ float layer2_row(
    const _Float16* __restrict__ h1,
    const int* __restrict__ row_ptr, const unsigned int* __restrict__ edges,
    const float* sW1, const float* sW2, const float* sb,
    int node, int lane)
{
    int es = row_ptr[node];
    int ee = row_ptr[node + 1];
    const float QS = 1.f / 16384.f;
    float g = 0.f;
    for (int base = es; base < ee; base += 64) {
        int cnt = min(64, ee - base);
        unsigned ev = (lane < cnt) ? edges[base + lane] : 0u;
        int j = 0;
        for (; j + 4 <= cnt; j += 4) {
            unsigned e0 = (unsigned)__shfl((int)ev, j);
            unsigned e1 = (unsigned)__shfl((int)ev, j + 1);
            unsigned e2 = (unsigned)__shfl((int)ev, j + 2);
            unsigned e3 = (unsigned)__shfl((int)ev, j + 3);
            float f0 = (float)h1[(size_t)(e0 >> 14) * 64 + lane];
            float f1 = (float)h1[(size_t)(e1 >> 14) * 64 + lane];
            float f2 = (float)h1[(size_t)(e2 >> 14) * 64 + lane];
            float f3 = (float)h1[(size_t)(e3 >> 14) * 64 + lane];
            g += (float)(e0 & 16383u) * QS * f0 + (float)(e1 & 16383u) * QS * f1
               + (float)(e2 & 16383u) * QS * f2 + (float)(e3 & 16383u) * QS * f3;
        }
        for (; j < cnt; j++) {
            unsigned e0 = (unsigned)__shfl((int)ev, j);
            float f0 = (float)h1[(size_t)(e0 >> 14) * 64 + lane];
            g += (float)(e0 & 16383u) * QS * f0;
        }
    }
    float f = (float)h1[(size_t)node * 64 + lane];
    float s = f + g;
    float p = f * g;
    int j = lane & 31;
    float acc = sb[j];
    #pragma unroll
    for (int k = 0; k < 64; k++) {
        float sk = __shfl(s, k);
        float pk = __shfl(p, k);
        acc += sk * sW1[k * 32 + j] + pk * sW2[k * 32 + j];
    }
    acc = (acc > 0.f) ? acc : 0.01f * acc;
    float sq = acc * acc;
    #pragma unroll
    for (int m = 1; m < 32; m <<= 1) sq += __shfl_xor(sq, m);
    return acc / fmaxf(sqrtf(sq), 1e-12f);
}

__global__ __launch_bounds__(256) void score_k(
    const float* __restrict__ uw, const float* __restrict__ ew,
    const _Float16* __restrict__ h1,
    const int* __restrict__ row_ptr, const unsigned int* __restrict__ edges,
    const float* __restrict__ W1b, const float* __restrict__ b1b,
    const float* __restrict__ W2b, const float* __restrict__ b2b,
    const int* __restrict__ uid, const int* __restrict__ pid,
    const int* __restrict__ nid, float* __restrict__ out)
{
    __shared__ float sW1[64 * 32];
    __shared__ float sW2[64 * 32];
    __shared__ float sb[32];
    for (int i = threadIdx.x; i < 64 * 32; i += 256) { sW1[i] = W1b[i]; sW2[i] = W2b[i]; }
    if (threadIdx.x < 32) sb[threadIdx.x] = b1b[threadIdx.x] + b2b[threadIdx.x];
    __syncthreads();

    int wave = threadIdx.x >> 6;
    int lane = threadIdx.x & 63;
    int i = blockIdx.x * 4 + wave;
    if (i >= BATCH_C) return;

    int un = uid[i];
    int pe = pid[i];
    int ne = nid[i];
    int pn = N_USERS + pe;
    int nn = N_USERS + ne;

    float acc01p, acc01n;
    {
        float u  = uw[(size_t)un * 64 + lane];
        float pv = ew[(size_t)pe * 64 + lane];
        float nv = ew[(size_t)ne * 64 + lane];
        acc01p = u * pv;
        acc01n = u * nv;
        float u1 = (float)h1[(size_t)un * 64 + lane];
        acc01p += u1 * (float)h1[(size_t)pn * 64 + lane];
        acc01n += u1 * (float)h1[(size_t)nn * 64 + lane];
    }

    float h2u = layer2_row(h1, row_ptr, edges, sW1, sW2, sb, un, lane);
    float h2p = layer2_row(h1, row_ptr, edges, sW1, sW2, sb, pn, lane);
    float h2n = layer2_row(h1, row_ptr, edges, sW1, sW2, sb, nn, lane);
    float p2 = h2u * h2p;
    float n2 = h2u * h2n;
    #pragma unroll
    for (int m = 1; m < 32; m <<= 1) { p2 += __shfl_xor(p2, m); n2 += __shfl_xor(n2, m); }

    #pragma unroll
    for (int m = 1; m < 64; m <<= 1) { acc01p += __shfl_xor(acc01p, m); acc01n += __shfl_xor(acc01n, m); }

    if (lane == 0) {
        out[i]           = acc01p + p2;
        out[BATCH_C + i] = acc01n + n2;
    }
}

extern "C" void kernel_launch(void* const* d_in, const int* in_sizes, int n_in,
                              void* d_out, int out_size, void* d_ws, size_t ws_size,
                              hipStream_t stream) {
    const float* uw   = (const float*)d_in[0];
    const float* ew   = (const float*)d_in[1];
    const float* W1a  = (const float*)d_in[2];
    const float* b1a  = (const float*)d_in[3];
    const float* W2a  = (const float*)d_in[4];
    const float* b2a  = (const float*)d_in[5];
    const float* W1b  = (const float*)d_in[6];
    const float* b1b  = (const float*)d_in[7];
    const float* W2b  = (const float*)d_in[8];
    const float* b2b  = (const float*)d_in[9];
    const float* values   = (const float*)d_in[10];
    const int*   target   = (const int*)d_in[11];
    const int*   neighbor = (const int*)d_in[12];
    const int*   uid  = (const int*)d_in[13];
    const int*   pid  = (const int*)d_in[14];
    const int*   nid  = (const int*)d_in[15];

    const int n_edges = in_sizes[10];

    char* ws = (char*)d_ws;
    int*  row_ptr    = (int*)ws;   ws += 801792;
    int*  cntarr     = (int*)ws;   ws += 704512;          // 448*391*4 = 700672
    int*  choff      = (int*)ws;   ws += 704512;
    int*  sgoff      = (int*)ws;   ws += 4096;
    unsigned int*   edges = (unsigned int*)ws;   ws += (size_t)N_EDGES_C * 4;      // 12.8 MB
    unsigned short* fb    = (unsigned short*)ws; ws += (size_t)N_NODES_C * 64 * 2; // 25.6 MB
    uint2*          tmp2  = (uint2*)ws;                   // aliased with h1
    _Float16*       h1    = (_Float16*)ws;                // region 25.69 MB

    const int layer_blocks = (N_NODES_C + 127) / 128;     // 1563
    const int conv_blocks  = (N_NODES_C * 64 + 255) / 256;
    const int nchunks      = (n_edges + CHUNK - 1) / CHUNK;   // 447

    // ----- f16 feature table -----
    tof16_k<<<conv_blocks, 256, 0, stream>>>(uw, ew, fb);

    // ----- edge sort + CSR build (no binary search anywhere) -----
    count_k<<<nchunks, 256, 0, stream>>>(target, cntarr, n_edges);
    sgscan_k<<<1, 512, 0, stream>>>(cntarr, choff, sgoff, nchunks);
    scatter_k<<<nchunks, 256, 0, stream>>>(target, neighbor, values, choff, tmp2, n_edges);
    sort2_k<<<NSG, 512, 0, stream>>>(tmp2, sgoff, row_ptr, edges);

    // ----- layer 1 (quad-node pull + MFMA transform, f16) -----
    layer1_pull_k<<<layer_blocks, 512, 0, stream>>>(fb, row_ptr, edges,
                                                    W1a, b1a, W2a, b2a, h1, N_NODES_C);

    // ----- scoring (layer-2 aggregation + transform inline, ~12K nodes) -----
    score_k<<<BATCH_C / 4, 256, 0, stream>>>(uw, ew, h1, row_ptr, edges,
                                             W1b, b1b, W2b, b2b,
                                             uid, pid, nid, (float*)d_out);
}

// Round 5
// 359.297 us; speedup vs baseline: 1.3798x; 1.2710x over previous
//
#include <hip/hip_runtime.h>

#define N_USERS    50000
#define N_ENTITIES 150000
#define N_NODES_C  200000
#define BATCH_C    4096
#define N_EDGES_C  3200000

// edge sort params
#define CHUNK   7168            // edges per scatter block (LDS 57.3 KB buf)
#define SG_SH   9               // supergroup = 512 nodes
#define NSG     391             // ceil(200000/512)

typedef __attribute__((ext_vector_type(2))) _Float16 h2;
typedef __attribute__((ext_vector_type(8))) _Float16 half8;
typedef __attribute__((ext_vector_type(2))) __fp16 fp16x2_s;   // builtin return type
typedef __attribute__((ext_vector_type(4))) float float4v;

// Workspace (~66 MB; proven safe < 76.8 MB):
//   row_ptr : int [200001+pad]      0.80 MB
//   sgtot   : int [512]             2 KB      (global per-sg edge totals, atomics)
//   sgoff   : int [512]             2 KB      (supergroup global starts)
//   sgcur   : int [512]             2 KB      (allocation cursor per sg)
//   edges   : uint [3.2M]          12.8 MB    (nb<<14 | val_q14, node-sorted CSR)
//   fb16    : ushort[200000*64]    25.6 MB    (f16 node features)
//   region  : 25.69 MB — tmp2 (uint2 sg-sorted edges) then h1 (f16 layer-1 out)
// Sort flow (NO serial chunk scan, NO binary search):
//   zero_k:    sgtot = 0
//   cnt_k:     per-chunk LDS histogram -> atomicAdd global sgtot
//   scan_k:    one 391-elem scan -> sgoff, init sgcur
//   scatter_k: LDS sg-sort chunk; per-sg base = atomicAdd(sgcur, cnt);
//              write runs coalesced to sg-contiguous tmp2 (order within sg
//              is arbitrary — sort2 re-sorts by node with atomics anyway)
//   sort2_k:   coalesced read of own sg segment, node-level count/scan/place

__device__ __forceinline__ h2 u2h(unsigned u) {
    union { unsigned u; h2 h; } x; x.u = u; return x.h;
}
__device__ __forceinline__ unsigned pk2h(float a, float b) {
    union { fp16x2_s h; unsigned u; } x;
    x.h = __builtin_amdgcn_cvt_pkrtz(a, b);
    return x.u;
}

// ---------- f16 node-feature table ----------
__global__ __launch_bounds__(256) void tof16_k(const float* __restrict__ uw,
                                               const float* __restrict__ ew,
                                               unsigned short* __restrict__ fb)
{
    int idx = blockIdx.x * 256 + threadIdx.x;
    if (idx >= N_NODES_C * 64) return;
    const int split = N_USERS * 64;
    float x = (idx < split) ? uw[idx] : ew[idx - split];
    _Float16 hx = (_Float16)x;
    fb[idx] = *(unsigned short*)&hx;
}

// ---------- zero the global sg totals ----------
__global__ __launch_bounds__(512) void zero_k(int* __restrict__ sgtot)
{
    if (threadIdx.x < NSG + 1) sgtot[threadIdx.x] = 0;
}

// ---------- pass A: per-chunk histogram -> global totals ----------
__global__ __launch_bounds__(256) void cnt_k(const int* __restrict__ target,
                                             int* __restrict__ sgtot, int n_edges)
{
    __shared__ int cnt[NSG];
    int c = blockIdx.x;
    int base = c * CHUNK;
    int ccount = min(CHUNK, n_edges - base);
    for (int i = threadIdx.x; i < NSG; i += 256) cnt[i] = 0;
    __syncthreads();
    for (int i = threadIdx.x; i < ccount; i += 256)
        atomicAdd(&cnt[target[base + i] >> SG_SH], 1);
    __syncthreads();
    for (int i = threadIdx.x; i < NSG; i += 256)
        if (cnt[i]) atomicAdd(&sgtot[i], cnt[i]);
}

// ---------- single small scan: sgoff + cursor init ----------
__global__ __launch_bounds__(512) void scan_k(const int* __restrict__ sgtot,
                                              int* __restrict__ sgoff,
                                              int* __restrict__ sgcur)
{
    __shared__ int part[512];
    int t = threadIdx.x;
    int v = (t < NSG) ? sgtot[t] : 0;
    part[t] = v;
    __syncthreads();
    for (int off = 1; off < 512; off <<= 1) {
        int w = (t >= off) ? part[t - off] : 0;
        __syncthreads();
        part[t] += w;
        __syncthreads();
    }
    if (t < NSG) { sgoff[t] = part[t] - v; sgcur[t] = part[t] - v; }
    if (t == NSG - 1) sgoff[NSG] = part[t];          // total = n_edges
}

// ---------- pass B: LDS sg-sort + cursor-allocated scatter to tmp2 ----------
__global__ __launch_bounds__(256) void scatter_k(
    const int* __restrict__ target, const int* __restrict__ neighbor,
    const float* __restrict__ values, int* __restrict__ sgcur,
    uint2* __restrict__ tmp2, int n_edges)
{
    __shared__ uint2 buf[CHUNK];            // 57.3 KB
    __shared__ int cnt[NSG], off[NSG], pos[NSG], gbase[NSG];
    int c = blockIdx.x;
    int base = c * CHUNK;
    int ccount = min(CHUNK, n_edges - base);
    for (int i = threadIdx.x; i < NSG; i += 256) { cnt[i] = 0; pos[i] = 0; }
    __syncthreads();
    for (int i = threadIdx.x; i < ccount; i += 256)
        atomicAdd(&cnt[target[base + i] >> SG_SH], 1);
    __syncthreads();
    // allocate this chunk's run for each sg on the global cursor
    for (int i = threadIdx.x; i < NSG; i += 256)
        if (cnt[i]) gbase[i] = atomicAdd(&sgcur[i], cnt[i]);
    if (threadIdx.x < 64) {                 // wave-0 exclusive scan of cnt
        int l = threadIdx.x;
        const int PER = (NSG + 63) / 64;    // 7
        int s0 = l * PER, s1 = min(s0 + PER, NSG);
        int sum = 0;
        for (int i = s0; i < s1; i++) sum += cnt[i];
        int run = sum;
        #pragma unroll
        for (int o = 1; o < 64; o <<= 1) { int v = __shfl_up(run, o); if (l >= o) run += v; }
        int excl = run - sum;
        for (int i = s0; i < s1; i++) { off[i] = excl; excl += cnt[i]; }
    }
    __syncthreads();
    for (int i = threadIdx.x; i < ccount; i += 256) {
        int t  = target[base + i];
        int sg = t >> SG_SH;
        unsigned q = (unsigned)fminf(values[base + i] * 16384.f + 0.5f, 16383.f);
        unsigned w = ((unsigned)neighbor[base + i] << 14) | q;
        int p = off[sg] + atomicAdd(&pos[sg], 1);
        buf[p] = make_uint2(w, (unsigned)t);
    }
    __syncthreads();
    // buf is sg-sorted: run for sg occupies [off[sg], off[sg]+cnt[sg]).
    // Write each run to its cursor-allocated global slot (coalesced within run).
    for (int i = threadIdx.x; i < ccount; i += 256) {
        uint2 ed = buf[i];
        int sg = (int)(ed.y >> SG_SH);
        tmp2[(size_t)(gbase[sg] + (i - off[sg]))] = ed;
    }
}

// ---------- stage 2: per-supergroup node-level CSR build (coalesced reads) ----------
__global__ __launch_bounds__(512) void sort2_k(
    const uint2* __restrict__ tmp2, const int* __restrict__ sgoff,
    int* __restrict__ row_ptr, unsigned* __restrict__ edges)
{
    __shared__ int cnt[512];
    __shared__ int cur[512];
    __shared__ int rp[513];
    int s = blockIdx.x;
    int node0 = s << SG_SH;
    int nn = min(512, N_NODES_C - node0);
    int sgstart = sgoff[s];
    int sgcnt = sgoff[s + 1] - sgstart;
    cnt[threadIdx.x] = 0;
    cur[threadIdx.x] = 0;
    __syncthreads();
    // pass 1: count per node (coalesced segment read)
    for (int e = threadIdx.x; e < sgcnt; e += 512)
        atomicAdd(&cnt[tmp2[(size_t)sgstart + e].y & 511u], 1);
    __syncthreads();
    if (threadIdx.x < 64) {                 // wave-0 exclusive scan of cnt[512]
        int l = threadIdx.x;
        int s0 = l * 8;
        int vals[8];
        int sum = 0;
        for (int i = 0; i < 8; i++) { vals[i] = cnt[s0 + i]; sum += vals[i]; }
        int run = sum;
        #pragma unroll
        for (int o = 1; o < 64; o <<= 1) { int v = __shfl_up(run, o); if (l >= o) run += v; }
        int excl = run - sum;
        for (int i = 0; i < 8; i++) { rp[s0 + i] = excl; excl += vals[i]; }
        if (l == 63) rp[512] = excl;
    }
    __syncthreads();
    for (int i = threadIdx.x; i < nn; i += 512) row_ptr[node0 + i] = sgstart + rp[i];
    if (s == NSG - 1 && threadIdx.x == 0) row_ptr[N_NODES_C] = sgstart + sgcnt;
    // pass 2: place (re-read is L2-hot)
    for (int e = threadIdx.x; e < sgcnt; e += 512) {
        uint2 ed = tmp2[(size_t)sgstart + e];
        int tl = (int)(ed.y & 511u);
        int old = atomicAdd(&cur[tl], 1);
        edges[sgstart + rp[tl] + old] = ed.x;
    }
}

// ---------- layer 1: quad-node gather pull (f16 pk_fma) + MFMA f16 transform ----------
// SPS=136 REQUIRED: each row holds 128 f16 k-values (64 sum + 64 product path).
#define SPS 136
__global__ __launch_bounds__(512, 6) void layer1_pull_k(
    const unsigned short* __restrict__ fb,
    const int* __restrict__ row_ptr, const unsigned int* __restrict__ edges,
    const float* __restrict__ W1, const float* __restrict__ b1,
    const float* __restrict__ W2, const float* __restrict__ b2,
    _Float16* __restrict__ h1out, int n_nodes)
{
    __shared__ __align__(16) short wt[64 * SPS];    // 17.4 KB
    __shared__ __align__(16) short sp[128 * SPS];   // 34.8 KB
    __shared__ float sbias[64];

    for (int idx = threadIdx.x; idx < 64 * 64; idx += 512) {
        int kp = idx >> 6;
        int n  = idx & 63;
        int k0 = kp * 2, k1 = k0 + 1;
        float w0 = (k0 < 64) ? W1[k0 * 64 + n] : W2[(k0 - 64) * 64 + n];
        float w1 = (k1 < 64) ? W1[k1 * 64 + n] : W2[(k1 - 64) * 64 + n];
        *(unsigned*)&wt[n * SPS + k0] = pk2h(w0, w1);
    }
    if (threadIdx.x < 64) sbias[threadIdx.x] = b1[threadIdx.x] + b2[threadIdx.x];
    __syncthreads();

    int wv   = threadIdx.x >> 6;
    int lane = threadIdx.x & 63;
    int g    = lane >> 4;
    int q    = lane & 15;
    const uint2* fb2 = (const uint2*)fb;

    int nb0 = blockIdx.x * 128;
    const float QS = 1.f / 16384.f;

    for (int i = 0; i < 16; i += 4) {
        int mA = wv * 16 + i;
        int nodeBase = nb0 + mA;

        int es0 = 0, ee0 = 0, es1 = 0, ee1 = 0, es2 = 0, ee2 = 0, es3 = 0, ee3 = 0;
        if (nodeBase     < n_nodes) { es0 = row_ptr[nodeBase];     ee0 = row_ptr[nodeBase + 1]; }
        if (nodeBase + 1 < n_nodes) { es1 = row_ptr[nodeBase + 1]; ee1 = row_ptr[nodeBase + 2]; }
        if (nodeBase + 2 < n_nodes) { es2 = row_ptr[nodeBase + 2]; ee2 = row_ptr[nodeBase + 3]; }
        if (nodeBase + 3 < n_nodes) { es3 = row_ptr[nodeBase + 3]; ee3 = row_ptr[nodeBase + 4]; }

        h2 aLo0 = (h2){0, 0}, aHi0 = (h2){0, 0};
        h2 aLo1 = (h2){0, 0}, aHi1 = (h2){0, 0};
        h2 aLo2 = (h2){0, 0}, aHi2 = (h2){0, 0};
        h2 aLo3 = (h2){0, 0}, aHi3 = (h2){0, 0};

        int b0 = es0, b1c = es1, b2c = es2, b3c = es3;
        while (b0 < ee0 || b1c < ee1 || b2c < ee2 || b3c < ee3) {
            int c0 = ee0 - b0;  c0 = c0 < 0 ? 0 : (c0 > 64 ? 64 : c0);
            int c1 = ee1 - b1c; c1 = c1 < 0 ? 0 : (c1 > 64 ? 64 : c1);
            int c2 = ee2 - b2c; c2 = c2 < 0 ? 0 : (c2 > 64 ? 64 : c2);
            int c3 = ee3 - b3c; c3 = c3 < 0 ? 0 : (c3 > 64 ? 64 : c3);
            unsigned ev0 = (lane < c0) ? edges[b0 + lane]  : 0u;
            unsigned ev1 = (lane < c1) ? edges[b1c + lane] : 0u;
            unsigned ev2 = (lane < c2) ? edges[b2c + lane] : 0u;
            unsigned ev3 = (lane < c3) ? edges[b3c + lane] : 0u;
            int jm0 = (c0 + 3) >> 2;
            int jm1 = (c1 + 3) >> 2;
            int jm2 = (c2 + 3) >> 2;
            int jm3 = (c3 + 3) >> 2;
            int jm = max(max(jm0, jm1), max(jm2, jm3));
            #pragma unroll 4
            for (int j = 0; j < jm; j++) {
                // lanes beyond a stream's count loaded 0 -> shfl yields w=0 -> v=0
                unsigned w0 = (unsigned)__shfl((int)ev0, j * 4 + g);
                unsigned w1 = (unsigned)__shfl((int)ev1, j * 4 + g);
                unsigned w2 = (unsigned)__shfl((int)ev2, j * 4 + g);
                unsigned w3 = (unsigned)__shfl((int)ev3, j * 4 + g);
                uint2 d0 = fb2[(size_t)(w0 >> 14) * 16 + q];
                uint2 d1 = fb2[(size_t)(w1 >> 14) * 16 + q];
                uint2 d2 = fb2[(size_t)(w2 >> 14) * 16 + q];
                uint2 d3 = fb2[(size_t)(w3 >> 14) * 16 + q];
                _Float16 v0 = (_Float16)((float)(w0 & 16383u) * QS);
                _Float16 v1 = (_Float16)((float)(w1 & 16383u) * QS);
                _Float16 v2 = (_Float16)((float)(w2 & 16383u) * QS);
                _Float16 v3 = (_Float16)((float)(w3 & 16383u) * QS);
                h2 vv0 = (h2){v0, v0};
                h2 vv1 = (h2){v1, v1};
                h2 vv2 = (h2){v2, v2};
                h2 vv3 = (h2){v3, v3};
                aLo0 += u2h(d0.x) * vv0;  aHi0 += u2h(d0.y) * vv0;
                aLo1 += u2h(d1.x) * vv1;  aHi1 += u2h(d1.y) * vv1;
                aLo2 += u2h(d2.x) * vv2;  aHi2 += u2h(d2.y) * vv2;
                aLo3 += u2h(d3.x) * vv3;  aHi3 += u2h(d3.y) * vv3;
            }
            b0 += 64; b1c += 64; b2c += 64; b3c += 64;
        }

        float ac[4][4];
        ac[0][0] = (float)aLo0.x; ac[0][1] = (float)aLo0.y; ac[0][2] = (float)aHi0.x; ac[0][3] = (float)aHi0.y;
        ac[1][0] = (float)aLo1.x; ac[1][1] = (float)aLo1.y; ac[1][2] = (float)aHi1.x; ac[1][3] = (float)aHi1.y;
        ac[2][0] = (float)aLo2.x; ac[2][1] = (float)aLo2.y; ac[2][2] = (float)aHi2.x; ac[2][3] = (float)aHi2.y;
        ac[3][0] = (float)aLo3.x; ac[3][1] = (float)aLo3.y; ac[3][2] = (float)aHi3.x; ac[3][3] = (float)aHi3.y;
        // reduce across the 4 lane-groups (bits 4,5 of lane id) in f32
        #pragma unroll
        for (int s = 0; s < 4; s++)
            #pragma unroll
            for (int c = 0; c < 4; c++) {
                ac[s][c] += __shfl_xor(ac[s][c], 16);
                ac[s][c] += __shfl_xor(ac[s][c], 32);
            }

        // epilogue: g pairs -> (row-pair, sum/product path); all 4 groups busy
        int hseg = g >> 1;
        int prod = g & 1;
        int r0 = mA + (hseg << 1);
        int r1 = r0 + 1;
        int nd0 = nb0 + r0, nd1 = nb0 + r1;
        uint2 d0 = make_uint2(0u, 0u), d1 = make_uint2(0u, 0u);
        if (nd0 < n_nodes) d0 = fb2[(size_t)nd0 * 16 + q];
        if (nd1 < n_nodes) d1 = fb2[(size_t)nd1 * 16 + q];
        float a00 = hseg ? ac[2][0] : ac[0][0];
        float a01 = hseg ? ac[2][1] : ac[0][1];
        float a02 = hseg ? ac[2][2] : ac[0][2];
        float a03 = hseg ? ac[2][3] : ac[0][3];
        float a10 = hseg ? ac[3][0] : ac[1][0];
        float a11 = hseg ? ac[3][1] : ac[1][1];
        float a12 = hseg ? ac[3][2] : ac[1][2];
        float a13 = hseg ? ac[3][3] : ac[1][3];
        h2 s0l = u2h(d0.x), s0h = u2h(d0.y);
        h2 s1l = u2h(d1.x), s1h = u2h(d1.y);
        float f00 = (float)s0l.x, f01 = (float)s0l.y, f02 = (float)s0h.x, f03 = (float)s0h.y;
        float f10 = (float)s1l.x, f11 = (float)s1l.y, f12 = (float)s1h.x, f13 = (float)s1h.y;
        float x00 = prod ? f00 * a00 : f00 + a00;
        float x01 = prod ? f01 * a01 : f01 + a01;
        float x02 = prod ? f02 * a02 : f02 + a02;
        float x03 = prod ? f03 * a03 : f03 + a03;
        float x10 = prod ? f10 * a10 : f10 + a10;
        float x11 = prod ? f11 * a11 : f11 + a11;
        float x12 = prod ? f12 * a12 : f12 + a12;
        float x13 = prod ? f13 * a13 : f13 + a13;
        uint2 pk;
        pk.x = pk2h(x00, x01);
        pk.y = pk2h(x02, x03);
        *(uint2*)&sp[r0 * SPS + prod * 64 + q * 4] = pk;
        pk.x = pk2h(x10, x11);
        pk.y = pk2h(x12, x13);
        *(uint2*)&sp[r1 * SPS + prod * 64 + q * 4] = pk;
    }

    // sp rows are wave-private: drain this wave's LDS writes only (no block barrier)
    __builtin_amdgcn_wave_barrier();
    asm volatile("s_waitcnt lgkmcnt(0)" ::: "memory");
    __builtin_amdgcn_wave_barrier();

    float4v c0, c1, c2, c3;
    {
        float bv0 = sbias[q];
        float bv1 = sbias[16 + q];
        float bv2 = sbias[32 + q];
        float bv3 = sbias[48 + q];
        c0 = (float4v){bv0, bv0, bv0, bv0};
        c1 = (float4v){bv1, bv1, bv1, bv1};
        c2 = (float4v){bv2, bv2, bv2, bv2};
        c3 = (float4v){bv3, bv3, bv3, bv3};
    }
    #pragma unroll
    for (int kk = 0; kk < 4; kk++) {
        int ko = kk * 32 + g * 8;
        half8 a   = *(const half8*)&sp[(wv * 16 + q) * SPS + ko];
        half8 bb0 = *(const half8*)&wt[(q)      * SPS + ko];
        half8 bb1 = *(const half8*)&wt[(16 + q) * SPS + ko];
        half8 bb2 = *(const half8*)&wt[(32 + q) * SPS + ko];
        half8 bb3 = *(const half8*)&wt[(48 + q) * SPS + ko];
        c0 = __builtin_amdgcn_mfma_f32_16x16x32_f16(a, bb0, c0, 0, 0, 0);
        c1 = __builtin_amdgcn_mfma_f32_16x16x32_f16(a, bb1, c1, 0, 0, 0);
        c2 = __builtin_amdgcn_mfma_f32_16x16x32_f16(a, bb2, c2, 0, 0, 0);
        c3 = __builtin_amdgcn_mfma_f32_16x16x32_f16(a, bb3, c3, 0, 0, 0);
    }

    float ss[4];
    #pragma unroll
    for (int r = 0; r < 4; r++) {
        c0[r] = (c0[r] > 0.f) ? c0[r] : 0.01f * c0[r];
        c1[r] = (c1[r] > 0.f) ? c1[r] : 0.01f * c1[r];
        c2[r] = (c2[r] > 0.f) ? c2[r] : 0.01f * c2[r];
        c3[r] = (c3[r] > 0.f) ? c3[r] : 0.01f * c3[r];
        ss[r] = c0[r]*c0[r] + c1[r]*c1[r] + c2[r]*c2[r] + c3[r]*c3[r];
        #pragma unroll
        for (int mm = 1; mm < 16; mm <<= 1) ss[r] += __shfl_xor(ss[r], mm);
        ss[r] = 1.f / fmaxf(sqrtf(ss[r]), 1e-12f);
    }
    #pragma unroll
    for (int r = 0; r < 4; r++) {
        int node_r = nb0 + wv * 16 + g * 4 + r;
        if (node_r >= n_nodes) continue;
        size_t row = (size_t)node_r * 64;
        h1out[row +      q] = (_Float16)(c0[r] * ss[r]);
        h1out[row + 16 + q] = (_Float16)(c1[r] * ss[r]);
        h1out[row + 32 + q] = (_Float16)(c2[r] * ss[r]);
        h1out[row + 48 + q] = (_Float16)(c3[r] * ss[r]);
    }
}

// ---------- inline layer2 (64->32) for one node ----------
__device__ __forceinline__ float layer2_row(
    const _Float16* __restrict__ h1,
    const int* __restrict__ row_ptr, const unsigned int* __restrict__ edges,
    const float* sW1, const float* sW2, const float* sb,
    int node, int lane)
{
    int es = row_ptr[node];
    int ee = row_ptr[node + 1];
    const float QS = 1.f / 16384.f;
    float g = 0.f;
    for (int base = es; base < ee; base += 64) {
        int cnt = min(64, ee - base);
        unsigned ev = (lane < cnt) ? edges[base + lane] : 0u;
        int j = 0;
        for (; j + 4 <= cnt; j += 4) {
            unsigned e0 = (unsigned)__shfl((int)ev, j);
            unsigned e1 = (unsigned)__shfl((int)ev, j + 1);
            unsigned e2 = (unsigned)__shfl((int)ev, j + 2);
            unsigned e3 = (unsigned)__shfl((int)ev, j + 3);
            float f0 = (float)h1[(size_t)(e0 >> 14) * 64 + lane];
            float f1 = (float)h1[(size_t)(e1 >> 14) * 64 + lane];
            float f2 = (float)h1[(size_t)(e2 >> 14) * 64 + lane];
            float f3 = (float)h1[(size_t)(e3 >> 14) * 64 + lane];
            g += (float)(e0 & 16383u) * QS * f0 + (float)(e1 & 16383u) * QS * f1
               + (float)(e2 & 16383u) * QS * f2 + (float)(e3 & 16383u) * QS * f3;
        }
        for (; j < cnt; j++) {
            unsigned e0 = (unsigned)__shfl((int)ev, j);
            float f0 = (float)h1[(size_t)(e0 >> 14) * 64 + lane];
            g += (float)(e0 & 16383u) * QS * f0;
        }
    }
    float f = (float)h1[(size_t)node * 64 + lane];
    float s = f + g;
    float p = f * g;
    int j = lane & 31;
    float acc = sb[j];
    #pragma unroll
    for (int k = 0; k < 64; k++) {
        float sk = __shfl(s, k);
        float pk = __shfl(p, k);
        acc += sk * sW1[k * 32 + j] + pk * sW2[k * 32 + j];
    }
    acc = (acc > 0.f) ? acc : 0.01f * acc;
    float sq = acc * acc;
    #pragma unroll
    for (int m = 1; m < 32; m <<= 1) sq += __shfl_xor(sq, m);
    return acc / fmaxf(sqrtf(sq), 1e-12f);
}

__global__ __launch_bounds__(256) void score_k(
    const float* __restrict__ uw, const float* __restrict__ ew,
    const _Float16* __restrict__ h1,
    const int* __restrict__ row_ptr, const unsigned int* __restrict__ edges,
    const float* __restrict__ W1b, const float* __restrict__ b1b,
    const float* __restrict__ W2b, const float* __restrict__ b2b,
    const int* __restrict__ uid, const int* __restrict__ pid,
    const int* __restrict__ nid, float* __restrict__ out)
{
    __shared__ float sW1[64 * 32];
    __shared__ float sW2[64 * 32];
    __shared__ float sb[32];
    for (int i = threadIdx.x; i < 64 * 32; i += 256) { sW1[i] = W1b[i]; sW2[i] = W2b[i]; }
    if (threadIdx.x < 32) sb[threadIdx.x] = b1b[threadIdx.x] + b2b[threadIdx.x];
    __syncthreads();

    int wave = threadIdx.x >> 6;
    int lane = threadIdx.x & 63;
    int i = blockIdx.x * 4 + wave;
    if (i >= BATCH_C) return;

    int un = uid[i];
    int pe = pid[i];
    int ne = nid[i];
    int pn = N_USERS + pe;
    int nn = N_USERS + ne;

    float acc01p, acc01n;
    {
        float u  = uw[(size_t)un * 64 + lane];
        float pv = ew[(size_t)pe * 64 + lane];
        float nv = ew[(size_t)ne * 64 + lane];
        acc01p = u * pv;
        acc01n = u * nv;
        float u1 = (float)h1[(size_t)un * 64 + lane];
        acc01p += u1 * (float)h1[(size_t)pn * 64 + lane];
        acc01n += u1 * (float)h1[(size_t)nn * 64 + lane];
    }

    float h2u = layer2_row(h1, row_ptr, edges, sW1, sW2, sb, un, lane);
    float h2p = layer2_row(h1, row_ptr, edges, sW1, sW2, sb, pn, lane);
    float h2n = layer2_row(h1, row_ptr, edges, sW1, sW2, sb, nn, lane);
    float p2 = h2u * h2p;
    float n2 = h2u * h2n;
    #pragma unroll
    for (int m = 1; m < 32; m <<= 1) { p2 += __shfl_xor(p2, m); n2 += __shfl_xor(n2, m); }

    #pragma unroll
    for (int m = 1; m < 64; m <<= 1) { acc01p += __shfl_xor(acc01p, m); acc01n += __shfl_xor(acc01n, m); }

    if (lane == 0) {
        out[i]           = acc01p + p2;
        out[BATCH_C + i] = acc01n + n2;
    }
}

extern "C" void kernel_launch(void* const* d_in, const int* in_sizes, int n_in,
                              void* d_out, int out_size, void* d_ws, size_t ws_size,
                              hipStream_t stream) {
    const float* uw   = (const float*)d_in[0];
    const float* ew   = (const float*)d_in[1];
    const float* W1a  = (const float*)d_in[2];
    const float* b1a  = (const float*)d_in[3];
    const float* W2a  = (const float*)d_in[4];
    const float* b2a  = (const float*)d_in[5];
    const float* W1b  = (const float*)d_in[6];
    const float* b1b  = (const float*)d_in[7];
    const float* W2b  = (const float*)d_in[8];
    const float* b2b  = (const float*)d_in[9];
    const float* values   = (const float*)d_in[10];
    const int*   target   = (const int*)d_in[11];
    const int*   neighbor = (const int*)d_in[12];
    const int*   uid  = (const int*)d_in[13];
    const int*   pid  = (const int*)d_in[14];
    const int*   nid  = (const int*)d_in[15];

    const int n_edges = in_sizes[10];

    char* ws = (char*)d_ws;
    int*  row_ptr    = (int*)ws;   ws += 801792;
    int*  sgtot      = (int*)ws;   ws += 4096;
    int*  sgoff      = (int*)ws;   ws += 4096;
    int*  sgcur      = (int*)ws;   ws += 4096;
    unsigned int*   edges = (unsigned int*)ws;   ws += (size_t)N_EDGES_C * 4;      // 12.8 MB
    unsigned short* fb    = (unsigned short*)ws; ws += (size_t)N_NODES_C * 64 * 2; // 25.6 MB
    uint2*          tmp2  = (uint2*)ws;                   // aliased with h1
    _Float16*       h1    = (_Float16*)ws;                // region 25.69 MB

    const int layer_blocks = (N_NODES_C + 127) / 128;     // 1563
    const int conv_blocks  = (N_NODES_C * 64 + 255) / 256;
    const int nchunks      = (n_edges + CHUNK - 1) / CHUNK;   // 447

    // ----- f16 feature table -----
    tof16_k<<<conv_blocks, 256, 0, stream>>>(uw, ew, fb);

    // ----- edge sort + CSR build (no serial chunk scan, no binary search) -----
    zero_k<<<1, 512, 0, stream>>>(sgtot);
    cnt_k<<<nchunks, 256, 0, stream>>>(target, sgtot, n_edges);
    scan_k<<<1, 512, 0, stream>>>(sgtot, sgoff, sgcur);
    scatter_k<<<nchunks, 256, 0, stream>>>(target, neighbor, values, sgcur, tmp2, n_edges);
    sort2_k<<<NSG, 512, 0, stream>>>(tmp2, sgoff, row_ptr, edges);

    // ----- layer 1 (quad-node pull + MFMA transform, f16) -----
    layer1_pull_k<<<layer_blocks, 512, 0, stream>>>(fb, row_ptr, edges,
                                                    W1a, b1a, W2a, b2a, h1, N_NODES_C);

    // ----- scoring (layer-2 aggregation + transform inline, ~12K nodes) -----
    score_k<<<BATCH_C / 4, 256, 0, stream>>>(uw, ew, h1, row_ptr, edges,
                                             W1b, b1b, W2b, b2b,
                                             uid, pid, nid, (float*)d_out);
}